// Round 4
// baseline (908.991 us; speedup 1.0000x reference)
//
#include <hip/hip_runtime.h>
#include <hip/hip_bf16.h>

#define NL 2048   // languages
#define DE 64     // embedding dim
#define VV 2048   // vocab
#define BT 64     // block pair-tile (64x64 pairs per block)
#define ST 68     // LDS row stride in floats (68%32==4 -> <=2-way aliasing, free)

// ws layout:
// [0:4)           uint max_bits
// [4:8)           uint mask_count
// [8:16)          double sum
// [16:8208)       int  perm[2048]   (sorted order -> original index)
// [8208:16400)    int  sids[2048]   (ids in sorted order)

__global__ void max_kernel(const float4* __restrict__ m, unsigned* __restrict__ wmax, int n4) {
    float v = 0.0f;  // map_dist values are >= 0
    for (int i = blockIdx.x * blockDim.x + threadIdx.x; i < n4; i += gridDim.x * blockDim.x) {
        float4 x = m[i];
        v = fmaxf(v, fmaxf(fmaxf(x.x, x.y), fmaxf(x.z, x.w)));
    }
    #pragma unroll
    for (int o = 32; o > 0; o >>= 1)
        v = fmaxf(v, __shfl_down(v, o));
    if ((threadIdx.x & 63) == 0)
        atomicMax(wmax, __float_as_uint(v));  // bit order == float order for v >= 0
}

// One block, 1024 threads: counting-sort 2048 ids entirely in LDS.
__global__ __launch_bounds__(1024) void sort_kernel(const int* __restrict__ ids,
                                                    int* __restrict__ perm,
                                                    int* __restrict__ sids) {
    __shared__ unsigned hist[VV];
    __shared__ unsigned offs[VV];
    __shared__ unsigned part[1024];
    const int t = threadIdx.x;

    hist[2 * t] = 0u; hist[2 * t + 1] = 0u;
    __syncthreads();

    const int id0 = ids[2 * t], id1 = ids[2 * t + 1];
    atomicAdd(&hist[id0], 1u);
    atomicAdd(&hist[id1], 1u);
    __syncthreads();

    const unsigned h0 = hist[2 * t], h1 = hist[2 * t + 1];
    const unsigned s = h0 + h1;
    part[t] = s;
    __syncthreads();
    for (int off = 1; off < 1024; off <<= 1) {
        unsigned v = (t >= off) ? part[t - off] : 0u;
        __syncthreads();
        part[t] += v;
        __syncthreads();
    }
    const unsigned ex = part[t] - s;  // exclusive prefix for bucket 2t
    offs[2 * t]     = ex;
    offs[2 * t + 1] = ex + h0;
    __syncthreads();

    unsigned p0 = atomicAdd(&offs[id0], 1u);
    perm[p0] = 2 * t;     sids[p0] = id0;
    unsigned p1 = atomicAdd(&offs[id1], 1u);
    perm[p1] = 2 * t + 1; sids[p1] = id1;
}

__global__ __launch_bounds__(256, 4) void loss_kernel(
    const float* __restrict__ emb,
    const float* __restrict__ tree, const float* __restrict__ mapd,
    const int* __restrict__ perm, const int* __restrict__ sids,
    const unsigned* __restrict__ wmax_bits,
    double* __restrict__ wsum, unsigned* __restrict__ wcnt)
{
    __shared__ __align__(16) float Ei[BT][ST];   // [i][dim]
    __shared__ __align__(16) float Ejt[DE][ST];  // [dim][j]  (transposed)
    __shared__ int idi[BT];
    __shared__ int idj[BT];

    const int tid = threadIdx.x;
    const int bi = blockIdx.x, bj = blockIdx.y;

    // ---- Stage tiles through perm (emb 512 KB -> L2-resident; rows fully used) ----
    {
        const int r  = tid & 63;          // row within tile
        const int c0 = (tid >> 6) << 4;   // dim chunk: 0,16,32,48
        const int gi = perm[bi * BT + r];
        const int gj = perm[bj * BT + r];
        const float4* pa = (const float4*)(emb + (size_t)gi * DE + c0);
        const float4* pb = (const float4*)(emb + (size_t)gj * DE + c0);
        float4 a0 = pa[0], a1 = pa[1], a2 = pa[2], a3 = pa[3];
        float4 b0 = pb[0], b1 = pb[1], b2 = pb[2], b3 = pb[3];
        *(float4*)&Ei[r][c0 + 0]  = a0;
        *(float4*)&Ei[r][c0 + 4]  = a1;
        *(float4*)&Ei[r][c0 + 8]  = a2;
        *(float4*)&Ei[r][c0 + 12] = a3;
        Ejt[c0 + 0][r]  = b0.x; Ejt[c0 + 1][r]  = b0.y; Ejt[c0 + 2][r]  = b0.z; Ejt[c0 + 3][r]  = b0.w;
        Ejt[c0 + 4][r]  = b1.x; Ejt[c0 + 5][r]  = b1.y; Ejt[c0 + 6][r]  = b1.z; Ejt[c0 + 7][r]  = b1.w;
        Ejt[c0 + 8][r]  = b2.x; Ejt[c0 + 9][r]  = b2.y; Ejt[c0 + 10][r] = b2.z; Ejt[c0 + 11][r] = b2.w;
        Ejt[c0 + 12][r] = b3.x; Ejt[c0 + 13][r] = b3.y; Ejt[c0 + 14][r] = b3.z; Ejt[c0 + 15][r] = b3.w;
        if (tid < BT)           idi[tid] = sids[bi * BT + tid];
        else if (tid < 2 * BT)  idj[tid - BT] = sids[bj * BT + (tid - BT)];
    }
    __syncthreads();

    const int ty = tid >> 4, tx = tid & 15;
    const int i0 = ty * 4, j0 = tx * 4;

    // ---- 4x4 register-tiled L1-distance accumulation (minimal live set) ----
    float acc[4][4];
    #pragma unroll
    for (int s = 0; s < 4; ++s)
        #pragma unroll
        for (int c = 0; c < 4; ++c) acc[s][c] = 0.0f;

    #pragma unroll
    for (int k = 0; k < 16; ++k) {        // dim chunk d = 4k
        float4 av[4], bv[4];
        #pragma unroll
        for (int s = 0; s < 4; ++s) av[s] = *(const float4*)&Ei[i0 + s][4 * k];
        #pragma unroll
        for (int c = 0; c < 4; ++c) bv[c] = *(const float4*)&Ejt[4 * k + c][j0];
        #pragma unroll
        for (int s = 0; s < 4; ++s) {
            acc[s][0] += fabsf(av[s].x - bv[0].x) + fabsf(av[s].y - bv[1].x)
                       + fabsf(av[s].z - bv[2].x) + fabsf(av[s].w - bv[3].x);
            acc[s][1] += fabsf(av[s].x - bv[0].y) + fabsf(av[s].y - bv[1].y)
                       + fabsf(av[s].z - bv[2].y) + fabsf(av[s].w - bv[3].y);
            acc[s][2] += fabsf(av[s].x - bv[0].z) + fabsf(av[s].y - bv[1].z)
                       + fabsf(av[s].z - bv[2].z) + fabsf(av[s].w - bv[3].z);
            acc[s][3] += fabsf(av[s].x - bv[0].w) + fabsf(av[s].y - bv[1].w)
                       + fabsf(av[s].z - bv[2].w) + fabsf(av[s].w - bv[3].w);
        }
    }

    // ---- Epilogue: fused metric gather + masked |diff| (sorted ids -> L2-local) ----
    const float inv = 1.0f / __uint_as_float(wmax_bits[0]);
    int ia[4], ja[4];
    #pragma unroll
    for (int s = 0; s < 4; ++s) { ia[s] = idi[i0 + s]; ja[s] = idj[j0 + s]; }
    float pp = 0.0f;
    unsigned cnt = 0;
    #pragma unroll
    for (int s = 0; s < 4; ++s)
        #pragma unroll
        for (int c = 0; c < 4; ++c) {
            const int off = ia[s] * VV + ja[c];
            const float metric = (tree[off] + mapd[off] * inv) * 0.5f;
            if (ia[s] != ja[c]) {
                pp += fabsf(acc[s][c] * (1.0f / (float)DE) - metric);
                cnt += 1u;
            }
        }

    // ---- Block reduction ----
    #pragma unroll
    for (int o = 32; o > 0; o >>= 1) {
        pp  += __shfl_down(pp, o);
        cnt += __shfl_down(cnt, o);
    }
    __shared__ float    wsum_l[4];
    __shared__ unsigned wcnt_l[4];
    const int wave = tid >> 6;
    if ((tid & 63) == 0) { wsum_l[wave] = pp; wcnt_l[wave] = cnt; }
    __syncthreads();
    if (tid == 0) {
        float    s = wsum_l[0] + wsum_l[1] + wsum_l[2] + wsum_l[3];
        unsigned c = wcnt_l[0] + wcnt_l[1] + wcnt_l[2] + wcnt_l[3];
        atomicAdd(wsum, (double)s);
        atomicAdd(wcnt, c);
    }
}

__global__ void finalize_kernel(const double* __restrict__ wsum,
                                const unsigned* __restrict__ wcnt,
                                float* __restrict__ out)
{
    if (threadIdx.x == 0 && blockIdx.x == 0)
        out[0] = (float)(wsum[0] / (double)wcnt[0]);
}

extern "C" void kernel_launch(void* const* d_in, const int* in_sizes, int n_in,
                              void* d_out, int out_size, void* d_ws, size_t ws_size,
                              hipStream_t stream) {
    const int*   ids  = (const int*)d_in[0];
    const float* emb  = (const float*)d_in[1];
    const float* tree = (const float*)d_in[2];
    const float* mapd = (const float*)d_in[3];
    float* out = (float*)d_out;

    unsigned* wmax = (unsigned*)d_ws;                        // [0:4)
    unsigned* wcnt = (unsigned*)((char*)d_ws + 4);           // [4:8)
    double*   wsum = (double*)((char*)d_ws + 8);             // [8:16)
    int*      perm = (int*)((char*)d_ws + 16);               // 2048 ints
    int*      sids = (int*)((char*)d_ws + 8208);             // 2048 ints

    hipMemsetAsync(d_ws, 0, 16, stream);

    max_kernel<<<1024, 256, 0, stream>>>((const float4*)mapd, wmax, (VV * VV) / 4);
    sort_kernel<<<1, 1024, 0, stream>>>(ids, perm, sids);

    dim3 grid(NL / BT, NL / BT);
    loss_kernel<<<grid, 256, 0, stream>>>(emb, tree, mapd, perm, sids, wmax, wsum, wcnt);

    finalize_kernel<<<1, 64, 0, stream>>>(wsum, wcnt, out);
}

// Round 5
// 168.775 us; speedup vs baseline: 5.3858x; 5.3858x over previous
//
#include <hip/hip_runtime.h>
#include <hip/hip_bf16.h>

#define NL 2048   // languages
#define DE 64     // embedding dim
#define VV 2048   // vocab
#define BT 64     // block pair-tile
#define ST 68     // LDS row stride (68%32==4 -> <=2-way bank aliasing, free)
#define NTILE (NL / BT)   // 32

// ws layout:
// [0:4)    uint max_bits     (zeroed)
// [4:8)    uint mask_count   (zeroed)
// [8:16)   double sum        (zeroed)
// [16:20)  uint done         (zeroed)
// [24:8216)    int perm[2048]
// [8216:16408) int sids[2048]

// Block 0: counting-sort the 2048 ids in LDS. Blocks 1..: grid-stride max(map_dist).
__global__ __launch_bounds__(1024) void prep_kernel(const int* __restrict__ ids,
                                                    const float4* __restrict__ m4, int n4,
                                                    unsigned* __restrict__ wmax,
                                                    int* __restrict__ perm,
                                                    int* __restrict__ sids) {
    const int t = threadIdx.x;
    if (blockIdx.x == 0) {
        __shared__ unsigned hist[VV];
        __shared__ unsigned offs[VV];
        __shared__ unsigned part[1024];
        hist[2 * t] = 0u; hist[2 * t + 1] = 0u;
        __syncthreads();
        const int id0 = ids[2 * t], id1 = ids[2 * t + 1];
        atomicAdd(&hist[id0], 1u);
        atomicAdd(&hist[id1], 1u);
        __syncthreads();
        const unsigned h0 = hist[2 * t], h1 = hist[2 * t + 1];
        const unsigned s = h0 + h1;
        part[t] = s;
        __syncthreads();
        for (int off = 1; off < 1024; off <<= 1) {
            unsigned v = (t >= off) ? part[t - off] : 0u;
            __syncthreads();
            part[t] += v;
            __syncthreads();
        }
        const unsigned ex = part[t] - s;
        offs[2 * t]     = ex;
        offs[2 * t + 1] = ex + h0;
        __syncthreads();
        unsigned p0 = atomicAdd(&offs[id0], 1u);
        perm[p0] = 2 * t;     sids[p0] = id0;
        unsigned p1 = atomicAdd(&offs[id1], 1u);
        perm[p1] = 2 * t + 1; sids[p1] = id1;
    } else {
        float v = 0.0f;  // map_dist >= 0
        for (int i = (blockIdx.x - 1) * 1024 + t; i < n4; i += (gridDim.x - 1) * 1024) {
            float4 x = m4[i];
            v = fmaxf(v, fmaxf(fmaxf(x.x, x.y), fmaxf(x.z, x.w)));
        }
        #pragma unroll
        for (int o = 32; o > 0; o >>= 1)
            v = fmaxf(v, __shfl_down(v, o));
        if ((t & 63) == 0)
            atomicMax(wmax, __float_as_uint(v));  // bit order == float order for v >= 0
    }
}

__global__ __launch_bounds__(256) void loss_kernel(
    const float* __restrict__ emb,
    const float* __restrict__ tree, const float* __restrict__ mapd,
    const int* __restrict__ perm, const int* __restrict__ sids,
    const unsigned* __restrict__ wmax_bits,
    double* __restrict__ wsum, unsigned* __restrict__ wcnt,
    unsigned* __restrict__ done, float* __restrict__ out)
{
    const int tid = threadIdx.x;
    const int bi = blockIdx.x, bj = blockIdx.y;

    if (bi <= bj) {   // symmetry: off-diagonal tiles counted x2, bi>bj tiles skipped
        __shared__ __align__(16) float Ei[BT][ST];   // [i][dim]
        __shared__ __align__(16) float Ejt[DE][ST];  // [dim][j]  (transposed)
        __shared__ int idi[BT];
        __shared__ int idj[BT];

        {
            const int r  = tid & 63;
            const int c0 = (tid >> 6) << 4;   // 0,16,32,48
            const int gi = perm[bi * BT + r];
            const int gj = perm[bj * BT + r];
            const float4* pa = (const float4*)(emb + (size_t)gi * DE + c0);
            const float4* pb = (const float4*)(emb + (size_t)gj * DE + c0);
            float4 a0 = pa[0], a1 = pa[1], a2 = pa[2], a3 = pa[3];
            float4 b0 = pb[0], b1 = pb[1], b2 = pb[2], b3 = pb[3];
            *(float4*)&Ei[r][c0 + 0]  = a0;
            *(float4*)&Ei[r][c0 + 4]  = a1;
            *(float4*)&Ei[r][c0 + 8]  = a2;
            *(float4*)&Ei[r][c0 + 12] = a3;
            Ejt[c0 + 0][r]  = b0.x; Ejt[c0 + 1][r]  = b0.y; Ejt[c0 + 2][r]  = b0.z; Ejt[c0 + 3][r]  = b0.w;
            Ejt[c0 + 4][r]  = b1.x; Ejt[c0 + 5][r]  = b1.y; Ejt[c0 + 6][r]  = b1.z; Ejt[c0 + 7][r]  = b1.w;
            Ejt[c0 + 8][r]  = b2.x; Ejt[c0 + 9][r]  = b2.y; Ejt[c0 + 10][r] = b2.z; Ejt[c0 + 11][r] = b2.w;
            Ejt[c0 + 12][r] = b3.x; Ejt[c0 + 13][r] = b3.y; Ejt[c0 + 14][r] = b3.z; Ejt[c0 + 15][r] = b3.w;
            if (tid < BT)           idi[tid] = sids[bi * BT + tid];
            else if (tid < 2 * BT)  idj[tid - BT] = sids[bj * BT + (tid - BT)];
        }
        __syncthreads();

        const int ty = tid >> 4, tx = tid & 15;
        const int i0 = ty * 4, j0 = tx * 4;

        float acc[4][4];
        #pragma unroll
        for (int s = 0; s < 4; ++s)
            #pragma unroll
            for (int c = 0; c < 4; ++c) acc[s][c] = 0.0f;

        // Limited unroll: keeps live set ~60-80 regs so the allocator neither
        // balloons to 256 nor spills (R2/R3/R4 all lost to this).
        #pragma unroll 2
        for (int k = 0; k < 16; ++k) {
            float4 av[4], bv[4];
            #pragma unroll
            for (int s = 0; s < 4; ++s) av[s] = *(const float4*)&Ei[i0 + s][4 * k];
            #pragma unroll
            for (int c = 0; c < 4; ++c) bv[c] = *(const float4*)&Ejt[4 * k + c][j0];
            #pragma unroll
            for (int s = 0; s < 4; ++s) {
                acc[s][0] += fabsf(av[s].x - bv[0].x) + fabsf(av[s].y - bv[1].x)
                           + fabsf(av[s].z - bv[2].x) + fabsf(av[s].w - bv[3].x);
                acc[s][1] += fabsf(av[s].x - bv[0].y) + fabsf(av[s].y - bv[1].y)
                           + fabsf(av[s].z - bv[2].y) + fabsf(av[s].w - bv[3].y);
                acc[s][2] += fabsf(av[s].x - bv[0].z) + fabsf(av[s].y - bv[1].z)
                           + fabsf(av[s].z - bv[2].z) + fabsf(av[s].w - bv[3].z);
                acc[s][3] += fabsf(av[s].x - bv[0].w) + fabsf(av[s].y - bv[1].w)
                           + fabsf(av[s].z - bv[2].w) + fabsf(av[s].w - bv[3].w);
            }
        }

        // Epilogue: fused metric gather (sorted ids -> tight L2 locality)
        const float inv = 1.0f / __uint_as_float(wmax_bits[0]);
        float pp = 0.0f;
        unsigned cnt = 0;
        #pragma unroll
        for (int s = 0; s < 4; ++s) {
            const int ia = idi[i0 + s];
            #pragma unroll
            for (int c = 0; c < 4; ++c) {
                const int ja = idj[j0 + c];
                const int off = ia * VV + ja;
                const float metric = (tree[off] + mapd[off] * inv) * 0.5f;
                if (ia != ja) {
                    pp += fabsf(acc[s][c] * (1.0f / (float)DE) - metric);
                    cnt += 1u;
                }
            }
        }

        #pragma unroll
        for (int o = 32; o > 0; o >>= 1) {
            pp  += __shfl_down(pp, o);
            cnt += __shfl_down(cnt, o);
        }
        __shared__ float    wsum_l[4];
        __shared__ unsigned wcnt_l[4];
        const int wave = tid >> 6;
        if ((tid & 63) == 0) { wsum_l[wave] = pp; wcnt_l[wave] = cnt; }
        __syncthreads();
        if (tid == 0) {
            const float    w = (bi == bj) ? 1.0f : 2.0f;
            const unsigned u = (bi == bj) ? 1u : 2u;
            float    s = wsum_l[0] + wsum_l[1] + wsum_l[2] + wsum_l[3];
            unsigned c = wcnt_l[0] + wcnt_l[1] + wcnt_l[2] + wcnt_l[3];
            atomicAdd(wsum, (double)(s * w));
            atomicAdd(wcnt, c * u);
        }
    }

    // All blocks (incl. early-exit) participate; last one finalizes.
    if (tid == 0) {
        __threadfence();
        const unsigned old = atomicAdd(done, 1u);
        if (old == (unsigned)(NTILE * NTILE) - 1u) {
            const double   S = atomicAdd(wsum, 0.0);
            const unsigned C = atomicAdd(wcnt, 0u);
            out[0] = (float)(S / (double)C);
        }
    }
}

extern "C" void kernel_launch(void* const* d_in, const int* in_sizes, int n_in,
                              void* d_out, int out_size, void* d_ws, size_t ws_size,
                              hipStream_t stream) {
    const int*   ids  = (const int*)d_in[0];
    const float* emb  = (const float*)d_in[1];
    const float* tree = (const float*)d_in[2];
    const float* mapd = (const float*)d_in[3];
    float* out = (float*)d_out;

    unsigned* wmax = (unsigned*)d_ws;                    // [0:4)
    unsigned* wcnt = (unsigned*)((char*)d_ws + 4);       // [4:8)
    double*   wsum = (double*)((char*)d_ws + 8);         // [8:16)
    unsigned* done = (unsigned*)((char*)d_ws + 16);      // [16:20)
    int*      perm = (int*)((char*)d_ws + 24);           // 2048 ints
    int*      sids = (int*)((char*)d_ws + 8216);         // 2048 ints

    hipMemsetAsync(d_ws, 0, 24, stream);

    prep_kernel<<<257, 1024, 0, stream>>>(ids, (const float4*)mapd, (VV * VV) / 4,
                                          wmax, perm, sids);

    dim3 grid(NTILE, NTILE);
    loss_kernel<<<grid, 256, 0, stream>>>(emb, tree, mapd, perm, sids, wmax,
                                          wsum, wcnt, done, out);
}

// Round 6
// 125.152 us; speedup vs baseline: 7.2631x; 1.3486x over previous
//
#include <hip/hip_runtime.h>
#include <hip/hip_bf16.h>

#define NL 2048   // languages
#define DE 64     // embedding dim
#define VV 2048   // vocab
#define BT 64     // block pair-tile
#define ST 68     // LDS row stride (68%32==4 -> <=2-way bank aliasing, free)
#define NTILE (NL / BT)   // 32

// ws layout:
// [0:4)    uint max_bits     (zeroed)
// [4:8)    uint mask_count   (zeroed)
// [8:16)   double sum        (zeroed)
// [16:20)  uint done         (zeroed)
// [24:8216)    int perm[2048]
// [8216:16408) int sids[2048]

// Block 0: counting-sort 2048 ids in LDS (2-barrier shuffle scan).
// Blocks 1..256: block-local max(map_dist) -> ONE atomicMax per block.
__global__ __launch_bounds__(1024) void prep_kernel(const int* __restrict__ ids,
                                                    const float4* __restrict__ m4,
                                                    unsigned* __restrict__ wmax,
                                                    int* __restrict__ perm,
                                                    int* __restrict__ sids) {
    const int t = threadIdx.x;
    const int lane = t & 63, wave = t >> 6;

    if (blockIdx.x == 0) {
        __shared__ unsigned hist[VV];
        __shared__ unsigned offs[VV];
        __shared__ unsigned wtot[16];
        hist[2 * t] = 0u; hist[2 * t + 1] = 0u;
        __syncthreads();
        const int id0 = ids[2 * t], id1 = ids[2 * t + 1];
        atomicAdd(&hist[id0], 1u);
        atomicAdd(&hist[id1], 1u);
        __syncthreads();
        const unsigned h0 = hist[2 * t], h1 = hist[2 * t + 1];
        const unsigned s = h0 + h1;
        // wave-level inclusive scan of s (no barriers)
        unsigned ps = s;
        #pragma unroll
        for (int o = 1; o < 64; o <<= 1) {
            unsigned u = __shfl_up(ps, o);
            if (lane >= o) ps += u;
        }
        if (lane == 63) wtot[wave] = ps;
        __syncthreads();
        // cross-wave exclusive offsets: wave 0 scans the 16 totals
        __shared__ unsigned wexc[16];
        if (wave == 0 && lane < 16) {
            unsigned v = wtot[lane];
            unsigned pv = v;
            #pragma unroll
            for (int o = 1; o < 16; o <<= 1) {
                unsigned u = __shfl_up(pv, o);
                if (lane >= o) pv += u;
            }
            wexc[lane] = pv - v;  // exclusive
        }
        __syncthreads();
        const unsigned ex = wexc[wave] + ps - s;  // global exclusive prefix for bucket 2t
        offs[2 * t]     = ex;
        offs[2 * t + 1] = ex + h0;
        __syncthreads();
        unsigned p0 = atomicAdd(&offs[id0], 1u);
        perm[p0] = 2 * t;     sids[p0] = id0;
        unsigned p1 = atomicAdd(&offs[id1], 1u);
        perm[p1] = 2 * t + 1; sids[p1] = id1;
    } else {
        // 256 max-blocks x 1024 threads x 4 float4 = 1M float4 = full 2048x2048
        const float4* p = m4 + (size_t)(blockIdx.x - 1) * 4096;
        const float4 x0 = p[t], x1 = p[t + 1024], x2 = p[t + 2048], x3 = p[t + 3072];
        float v = fmaxf(fmaxf(fmaxf(x0.x, x0.y), fmaxf(x0.z, x0.w)),
                        fmaxf(fmaxf(x1.x, x1.y), fmaxf(x1.z, x1.w)));
        v = fmaxf(v, fmaxf(fmaxf(x2.x, x2.y), fmaxf(x2.z, x2.w)));
        v = fmaxf(v, fmaxf(fmaxf(x3.x, x3.y), fmaxf(x3.z, x3.w)));
        #pragma unroll
        for (int o = 32; o > 0; o >>= 1)
            v = fmaxf(v, __shfl_down(v, o));
        __shared__ float wmax_l[16];
        if (lane == 0) wmax_l[wave] = v;
        __syncthreads();
        if (wave == 0) {
            float m = (lane < 16) ? wmax_l[lane] : 0.0f;
            #pragma unroll
            for (int o = 8; o > 0; o >>= 1)
                m = fmaxf(m, __shfl_down(m, o));
            if (lane == 0)
                atomicMax(wmax, __float_as_uint(m));  // 256 atomics total (was 4096)
        }
    }
}

__global__ __launch_bounds__(256) void loss_kernel(
    const float* __restrict__ emb,
    const float* __restrict__ tree, const float* __restrict__ mapd,
    const int* __restrict__ perm, const int* __restrict__ sids,
    const unsigned* __restrict__ wmax_bits,
    double* __restrict__ wsum, unsigned* __restrict__ wcnt,
    unsigned* __restrict__ done, float* __restrict__ out)
{
    const int tid = threadIdx.x;
    const int bi = blockIdx.x, bj = blockIdx.y;

    if (bi <= bj) {   // symmetry: off-diagonal tiles counted x2, bi>bj tiles skipped
        __shared__ __align__(16) float Ei[BT][ST];   // [i][dim]
        __shared__ __align__(16) float Ejt[DE][ST];  // [dim][j]  (transposed)
        __shared__ int idi[BT];
        __shared__ int idj[BT];

        {
            const int r  = tid & 63;
            const int c0 = (tid >> 6) << 4;   // 0,16,32,48
            const int gi = perm[bi * BT + r];
            const int gj = perm[bj * BT + r];
            const float4* pa = (const float4*)(emb + (size_t)gi * DE + c0);
            const float4* pb = (const float4*)(emb + (size_t)gj * DE + c0);
            float4 a0 = pa[0], a1 = pa[1], a2 = pa[2], a3 = pa[3];
            float4 b0 = pb[0], b1 = pb[1], b2 = pb[2], b3 = pb[3];
            *(float4*)&Ei[r][c0 + 0]  = a0;
            *(float4*)&Ei[r][c0 + 4]  = a1;
            *(float4*)&Ei[r][c0 + 8]  = a2;
            *(float4*)&Ei[r][c0 + 12] = a3;
            Ejt[c0 + 0][r]  = b0.x; Ejt[c0 + 1][r]  = b0.y; Ejt[c0 + 2][r]  = b0.z; Ejt[c0 + 3][r]  = b0.w;
            Ejt[c0 + 4][r]  = b1.x; Ejt[c0 + 5][r]  = b1.y; Ejt[c0 + 6][r]  = b1.z; Ejt[c0 + 7][r]  = b1.w;
            Ejt[c0 + 8][r]  = b2.x; Ejt[c0 + 9][r]  = b2.y; Ejt[c0 + 10][r] = b2.z; Ejt[c0 + 11][r] = b2.w;
            Ejt[c0 + 12][r] = b3.x; Ejt[c0 + 13][r] = b3.y; Ejt[c0 + 14][r] = b3.z; Ejt[c0 + 15][r] = b3.w;
            if (tid < BT)           idi[tid] = sids[bi * BT + tid];
            else if (tid < 2 * BT)  idj[tid - BT] = sids[bj * BT + (tid - BT)];
        }
        __syncthreads();

        const int ty = tid >> 4, tx = tid & 15;
        const int i0 = ty * 4, j0 = tx * 4;

        float acc[4][4];
        #pragma unroll
        for (int s = 0; s < 4; ++s)
            #pragma unroll
            for (int c = 0; c < 4; ++c) acc[s][c] = 0.0f;

        // unroll 2: keeps live set ~60-80 regs (full unroll spilled in R2/R3/R4)
        #pragma unroll 2
        for (int k = 0; k < 16; ++k) {
            float4 av[4], bv[4];
            #pragma unroll
            for (int s = 0; s < 4; ++s) av[s] = *(const float4*)&Ei[i0 + s][4 * k];
            #pragma unroll
            for (int c = 0; c < 4; ++c) bv[c] = *(const float4*)&Ejt[4 * k + c][j0];
            #pragma unroll
            for (int s = 0; s < 4; ++s) {
                acc[s][0] += fabsf(av[s].x - bv[0].x) + fabsf(av[s].y - bv[1].x)
                           + fabsf(av[s].z - bv[2].x) + fabsf(av[s].w - bv[3].x);
                acc[s][1] += fabsf(av[s].x - bv[0].y) + fabsf(av[s].y - bv[1].y)
                           + fabsf(av[s].z - bv[2].y) + fabsf(av[s].w - bv[3].y);
                acc[s][2] += fabsf(av[s].x - bv[0].z) + fabsf(av[s].y - bv[1].z)
                           + fabsf(av[s].z - bv[2].z) + fabsf(av[s].w - bv[3].z);
                acc[s][3] += fabsf(av[s].x - bv[0].w) + fabsf(av[s].y - bv[1].w)
                           + fabsf(av[s].z - bv[2].w) + fabsf(av[s].w - bv[3].w);
            }
        }

        // Epilogue: fused metric gather (sorted ids -> tight L2 locality)
        const float inv = 1.0f / __uint_as_float(wmax_bits[0]);
        float pp = 0.0f;
        unsigned cnt = 0;
        #pragma unroll
        for (int s = 0; s < 4; ++s) {
            const int ia = idi[i0 + s];
            #pragma unroll
            for (int c = 0; c < 4; ++c) {
                const int ja = idj[j0 + c];
                const int off = ia * VV + ja;
                const float metric = (tree[off] + mapd[off] * inv) * 0.5f;
                if (ia != ja) {
                    pp += fabsf(acc[s][c] * (1.0f / (float)DE) - metric);
                    cnt += 1u;
                }
            }
        }

        #pragma unroll
        for (int o = 32; o > 0; o >>= 1) {
            pp  += __shfl_down(pp, o);
            cnt += __shfl_down(cnt, o);
        }
        __shared__ float    wsum_l[4];
        __shared__ unsigned wcnt_l[4];
        const int wave = tid >> 6;
        if ((tid & 63) == 0) { wsum_l[wave] = pp; wcnt_l[wave] = cnt; }
        __syncthreads();
        if (tid == 0) {
            const float    w = (bi == bj) ? 1.0f : 2.0f;
            const unsigned u = (bi == bj) ? 1u : 2u;
            float    s = wsum_l[0] + wsum_l[1] + wsum_l[2] + wsum_l[3];
            unsigned c = wcnt_l[0] + wcnt_l[1] + wcnt_l[2] + wcnt_l[3];
            atomicAdd(wsum, (double)(s * w));
            atomicAdd(wcnt, c * u);
        }
    }

    // All blocks (incl. early-exit) participate; last one finalizes.
    if (tid == 0) {
        __threadfence();
        const unsigned old = atomicAdd(done, 1u);
        if (old == (unsigned)(NTILE * NTILE) - 1u) {
            const double   S = atomicAdd(wsum, 0.0);
            const unsigned C = atomicAdd(wcnt, 0u);
            out[0] = (float)(S / (double)C);
        }
    }
}

extern "C" void kernel_launch(void* const* d_in, const int* in_sizes, int n_in,
                              void* d_out, int out_size, void* d_ws, size_t ws_size,
                              hipStream_t stream) {
    const int*   ids  = (const int*)d_in[0];
    const float* emb  = (const float*)d_in[1];
    const float* tree = (const float*)d_in[2];
    const float* mapd = (const float*)d_in[3];
    float* out = (float*)d_out;

    unsigned* wmax = (unsigned*)d_ws;                    // [0:4)
    unsigned* wcnt = (unsigned*)((char*)d_ws + 4);       // [4:8)
    double*   wsum = (double*)((char*)d_ws + 8);         // [8:16)
    unsigned* done = (unsigned*)((char*)d_ws + 16);      // [16:20)
    int*      perm = (int*)((char*)d_ws + 24);           // 2048 ints
    int*      sids = (int*)((char*)d_ws + 8216);         // 2048 ints

    hipMemsetAsync(d_ws, 0, 24, stream);

    prep_kernel<<<257, 1024, 0, stream>>>(ids, (const float4*)mapd, wmax, perm, sids);

    dim3 grid(NTILE, NTILE);
    loss_kernel<<<grid, 256, 0, stream>>>(emb, tree, mapd, perm, sids, wmax,
                                          wsum, wcnt, done, out);
}